// Round 1
// 607.113 us; speedup vs baseline: 1.1735x; 1.1735x over previous
//
#include <hip/hip_runtime.h>
#include <hip/hip_bf16.h>

#define Nn 4
#define CIN 2048
#define Hh 59
#define Ww 59
#define HW 3481
#define MID 512
#define MMpad 3584       // 3481 padded to mult of 64
#define SW 30
#define SP 900
#define PP 1024          // pixels padded
#define EPSF 1e-5f

typedef __hip_bfloat16 bf16;
typedef __attribute__((ext_vector_type(8))) short short8;
typedef __attribute__((ext_vector_type(4))) float floatx4;
typedef unsigned short u16;

__device__ __forceinline__ float b2f(u16 u) { return __uint_as_float(((unsigned)u) << 16); }
__device__ __forceinline__ u16 f2b(float f) {
    unsigned u = __float_as_uint(f);
    return (u16)((u + 0x7FFF + ((u >> 16) & 1)) >> 16);  // RNE
}

// ---------------- dtype probe: bf16 vs fp32 ----------------
__global__ void probe_k(const u16* __restrict__ x, int* __restrict__ flag)
{
    __shared__ int cnt;
    if (threadIdx.x == 0) cnt = 0;
    __syncthreads();
    int local = 0;
    for (int i = threadIdx.x; i < 8192; i += 256) {
        u16 u = x[i];
        int e = (u >> 7) & 0xFF;
        if (u != 0 && (e < 90 || e > 160)) local++;
    }
    atomicAdd(&cnt, local);
    __syncthreads();
    if (threadIdx.x == 0) *flag = (cnt > 256) ? 1 : 0;   // 1 = fp32
}

__device__ __forceinline__ float load_in(const void* p, long i, int isf32)
{
    return isf32 ? ((const float*)p)[i] : b2f(((const u16*)p)[i]);
}

// ---------------- weight staging -> bf16 bits (all 7 in one launch) --------
struct WArgs {
    const void* src[7];
    u16* dst[7];
    long n[7];
};

__global__ __launch_bounds__(256) void wconv_all(WArgs a, const int* __restrict__ flag)
{
    const int s = blockIdx.y;
    const long n = a.n[s];
    const int f = *flag;
    const u16* su = (const u16*)a.src[s];
    const float* sf = (const float*)a.src[s];
    u16* d = a.dst[s];
    for (long i = (long)blockIdx.x * 256 + threadIdx.x; i < n; i += (long)gridDim.x * 256) {
        d[i] = f ? f2b(sf[i]) : su[i];
    }
}

// ---------------- BN prep (all 5 in one launch) ----------------------------
// dst layout: [scale(C)... | bias at dst[sbN + c] ]
struct BArgs {
    const void* src[5];
    float* dst[5];
    int C[5];
    int sbN[5];
};

__global__ __launch_bounds__(256) void bnprep_all(BArgs a, const int* __restrict__ flag)
{
    const int s = blockIdx.y;
    const int C = a.C[s];
    const int c = blockIdx.x * 256 + threadIdx.x;
    if (c >= C) return;
    const int f = *flag;
    const void* bnp = a.src[s];
    float g = load_in(bnp, c, f);
    float b = load_in(bnp, C + c, f);
    float m = load_in(bnp, 2 * C + c, f);
    float v = load_in(bnp, 3 * C + c, f);
    float sc = g / sqrtf(v + EPSF);
    float* dst = a.dst[s];
    dst[c] = sc;
    dst[a.sbN[s] + c] = b - m * sc;
}

// ---------------- subsample + transpose: x[n][c][::2,::2] -> xsT[n][p][c] ----
__global__ __launch_bounds__(256) void subsampleT_k(const void* __restrict__ x,
                                                    u16* __restrict__ xsT,
                                                    const int* __restrict__ flag)
{
    __shared__ u16 ls[64][34];
    const int c0 = blockIdx.x * 64;
    const int a  = blockIdx.y;          // 0..29
    const int n  = blockIdx.z;
    const int tid = threadIdx.x;
    const int f = *flag;
    for (int idx = tid; idx < 1920; idx += 256) {
        int ci = idx / 30, b = idx - 30 * (idx / 30);
        float v = load_in(x, ((long)n * CIN + c0 + ci) * HW + a * 118 + 2 * b, f);
        ls[ci][b] = f2b(v);
    }
    __syncthreads();
    for (int idx = tid; idx < 1920; idx += 256) {
        int b = idx >> 6, ci = idx & 63;
        xsT[((long)n * PP + a * 30 + b) * CIN + c0 + ci] = ls[ci][b];
    }
}

// ---------------- identity copy: x -> out first CIN channels ----------------
__global__ __launch_bounds__(256) void copyx_k(const void* __restrict__ x,
                                               void* __restrict__ out,
                                               const int* __restrict__ flag)
{
    long i = (long)blockIdx.x * 256 + threadIdx.x;
    if (*flag) {
        const long per = 1782272;  // uint4 per batch (fp32)
        if (i >= Nn * per) return;
        long n = i / per, r = i - n * per;
        ((uint4*)out)[n * 2 * per + r] = ((const uint4*)x)[i];
    } else {
        const long per = 891136;   // uint4 per batch (bf16)
        if (i >= Nn * per) return;
        long n = i / per, r = i - n * per;
        ((uint4*)out)[n * 2 * per + r] = ((const uint4*)x)[i];
    }
}

// ---------------- MFMA GEMM v2 --------------------------------------------
// C[M][N] = A[M][K] * B[N][K]^T, tile BM=128, BN=64, BK=64.
// 256 threads = 4 waves, each computing 64x32 (4x2 of 16x16x32).
// Staging: global_load_lds 16B with XOR-swizzled GLOBAL source (LDS dest stays
// linear per HW requirement); reads use the same XOR -> 2-way (free) bank
// pattern instead of the previous layout's 8-way conflicts.
// z-grouping: zi = z % zGrp, zg = z / zGrp; ptr += zi*s + zg*s2. Lets one
// launch cover {batch x branch} with different weight/BN pointers per branch.
__device__ __forceinline__ void gl2lds16(const void* g, void* l)
{
    __builtin_amdgcn_global_load_lds(
        (const __attribute__((address_space(1))) void*)g,
        (__attribute__((address_space(3))) void*)l, 16, 0, 0);
}

__global__ __launch_bounds__(256) void mfma_gemm(
    const u16* __restrict__ A, long sA, long sA2,
    const u16* __restrict__ B, long sB, long sB2,
    u16* __restrict__ C, long sC, long sC2, int zGrp,
    int ldc, int K,
    const float* __restrict__ sb, int sbN, long sbStride, int relu)
{
    __shared__ __align__(16) u16 As[128 * 64];   // 16 KB
    __shared__ __align__(16) u16 Bs[64 * 64];    //  8 KB
    const int z = blockIdx.z;
    const int zi = z % zGrp, zg = z / zGrp;
    const int tid = threadIdx.x;
    const int lane = tid & 63;
    const int w = tid >> 6;
    const int m_base = blockIdx.y * 128;
    const int n_base = blockIdx.x * 64;
    const u16* Az = A + (long)zi * sA + (long)zg * sA2;
    const u16* Bz = B + (long)zi * sB + (long)zg * sB2;
    u16* Cz = C + (long)zi * sC + (long)zg * sC2;
    const float* sbz = sb ? sb + (long)zg * sbStride : (const float*)0;

    const int quad = lane >> 4;
    const int l15 = lane & 15;
    const int wr = w >> 1, wc = w & 1;
    const int r8 = lane >> 3, c8 = lane & 7;
    const int swz = (c8 ^ r8) * 8;             // swizzled k-chunk (u16 units)

    const long aRow = m_base + w * 32 + r8;    // + i*8
    const long bRow = n_base + w * 16 + r8;    // + j*8

    floatx4 acc[4][2] = {};

    for (int k0 = 0; k0 < K; k0 += 64) {
        #pragma unroll
        for (int i = 0; i < 4; i++)
            gl2lds16(Az + (aRow + i * 8) * K + k0 + swz,
                     &As[w * 2048 + i * 512 + lane * 8]);
        #pragma unroll
        for (int j = 0; j < 2; j++)
            gl2lds16(Bz + (bRow + j * 8) * K + k0 + swz,
                     &Bs[w * 1024 + j * 512 + lane * 8]);
        __syncthreads();
        #pragma unroll
        for (int kk = 0; kk < 2; kk++) {
            const int sw = ((kk * 4 + quad) ^ (l15 & 7)) * 8;
            short8 af[4], bfv[2];
            #pragma unroll
            for (int t = 0; t < 4; t++)
                af[t] = *(const short8*)&As[(wr * 64 + t * 16 + l15) * 64 + sw];
            #pragma unroll
            for (int u = 0; u < 2; u++)
                bfv[u] = *(const short8*)&Bs[(wc * 32 + u * 16 + l15) * 64 + sw];
            #pragma unroll
            for (int t = 0; t < 4; t++)
                #pragma unroll
                for (int u = 0; u < 2; u++)
                    acc[t][u] = __builtin_amdgcn_mfma_f32_16x16x32_bf16(af[t], bfv[u], acc[t][u], 0, 0, 0);
        }
        __syncthreads();
    }

    #pragma unroll
    for (int u = 0; u < 2; u++) {
        int n = n_base + wc * 32 + u * 16 + l15;
        float scale = 1.f, bias = 0.f;
        if (sbz) { scale = sbz[n]; bias = sbz[sbN + n]; }
        #pragma unroll
        for (int t = 0; t < 4; t++) {
            int mrow = m_base + wr * 64 + t * 16 + quad * 4;
            #pragma unroll
            for (int r = 0; r < 4; r++) {
                float v = acc[t][u][r];
                v = v * scale + bias;
                if (relu) v = fmaxf(v, 0.f);
                Cz[(long)(mrow + r) * ldc + n] = f2b(v);
            }
        }
    }
}

// ---------------- batched 64x64 tiled transpose (bf16 bits) ----------------
__global__ __launch_bounds__(256) void transpose64_k(const u16* __restrict__ in,
                                                     u16* __restrict__ out,
                                                     int R, int Cc, long sIn, long sOut)
{
    __shared__ u16 ls[64][66];
    const int c0 = blockIdx.x * 64;
    const int r0 = blockIdx.y * 64;
    const int z = blockIdx.z;
    const int tid = threadIdx.x;
    const int t63 = tid & 63, t2 = tid >> 6;
    #pragma unroll
    for (int s = 0; s < 16; s++) {
        int rl = t2 + s * 4;
        ls[rl][t63] = in[(long)z * sIn + (long)(r0 + rl) * Cc + c0 + t63];
    }
    __syncthreads();
    #pragma unroll
    for (int s = 0; s < 16; s++) {
        int cl = t2 + s * 4;
        out[(long)z * sOut + (long)(c0 + cl) * R + r0 + t63] = ls[t63][cl];
    }
}

// ---------------- gather + softmax: y_t[n][p][m3584] -> P_t[n][ab][ij] -----
__global__ __launch_bounds__(256) void softmax_gather_k(const u16* __restrict__ y,
                                                        u16* __restrict__ P,
                                                        int collect)
{
    const int ab = blockIdx.x;      // 0..899
    const int n = blockIdx.y;
    const int a = ab / SW, b = ab - a * SW;
    const int t = threadIdx.x;
    __shared__ float red[4];

    float vals[4];
    float mx = -1e30f;
    #pragma unroll
    for (int q = 0; q < 4; q++) {
        int ij = t + q * 256;
        float v = -1e30f;
        if (ij < SP) {
            int i = ij / SW, j = ij - (ij / SW) * SW;
            long idx;
            if (collect) idx = ((long)n * PP + ab) * MMpad + (i - a + 29) * 59 + (j - b + 29);
            else         idx = ((long)n * PP + ij) * MMpad + (a - i + 29) * 59 + (b - j + 29);
            v = b2f(y[idx]);
        }
        vals[q] = v;
        mx = fmaxf(mx, v);
    }
    #pragma unroll
    for (int off = 32; off; off >>= 1) mx = fmaxf(mx, __shfl_xor(mx, off, 64));
    if ((t & 63) == 0) red[t >> 6] = mx;
    __syncthreads();
    mx = fmaxf(fmaxf(red[0], red[1]), fmaxf(red[2], red[3]));
    __syncthreads();

    float s = 0.f;
    #pragma unroll
    for (int q = 0; q < 4; q++) {
        if (vals[q] > -1e29f) { vals[q] = expf(vals[q] - mx); s += vals[q]; }
        else vals[q] = 0.f;
    }
    #pragma unroll
    for (int off = 32; off; off >>= 1) s += __shfl_xor(s, off, 64);
    if ((t & 63) == 0) red[t >> 6] = s;
    __syncthreads();
    s = red[0] + red[1] + red[2] + red[3];
    float inv = 1.f / s;
    #pragma unroll
    for (int q = 0; q < 4; q++) {
        int ij = t + q * 256;
        if (ij < SP) P[((long)n * PP + ab) * PP + ij] = f2b(vals[q] * inv);
    }
}

// ---------------- 2x upsample from xp_t[n][p][c], write out 2nd half --------
__global__ __launch_bounds__(256) void upsample_k(const u16* __restrict__ xp,
                                                  void* __restrict__ out,
                                                  const int* __restrict__ flag)
{
    __shared__ u16 ls[2][30][66];
    const int o0 = blockIdx.x * 64;
    const int y  = blockIdx.y;          // 0..58
    const int n  = blockIdx.z;
    const int tid = threadIdx.x;
    const int i = y >> 1;
    const int i1 = (i + 1 < 30) ? i + 1 : 29;
    const int c = tid & 63;
    for (int row = tid >> 6; row < 60; row += 4) {
        int r = row / 30, j = row - 30 * (row / 30);
        int pr = (r == 0) ? i : i1;
        ls[r][j][c] = xp[((long)n * PP + pr * 30 + j) * CIN + o0 + c];
    }
    __syncthreads();
    const int xcol = tid & 63;
    const int oi = tid >> 6;
    if (xcol < 59) {
        int j = xcol >> 1;
        bool xe = !(xcol & 1), ye = !(y & 1);
        int f = *flag;
        for (int oo = oi; oo < 64; oo += 4) {
            float v00 = b2f(ls[0][j][oo]);
            float v;
            if (ye && xe)      v = v00;
            else if (ye)       v = 0.5f * (v00 + b2f(ls[0][j + 1][oo]));
            else if (xe)       v = 0.5f * (v00 + b2f(ls[1][j][oo]));
            else               v = 0.25f * (v00 + b2f(ls[0][j + 1][oo])
                                          + b2f(ls[1][j][oo]) + b2f(ls[1][j + 1][oo]));
            long oidx = ((long)n * (2 * CIN) + CIN + o0 + oo) * HW + (long)y * 59 + xcol;
            if (f) ((float*)out)[oidx] = v;
            else   ((u16*)out)[oidx] = f2b(v);
        }
    }
}

// ---------------- launch ----------------
extern "C" void kernel_launch(void* const* d_in, const int* in_sizes, int n_in,
                              void* d_out, int out_size, void* d_ws, size_t ws_size,
                              hipStream_t stream)
{
    const void* x    = d_in[0];
    const void* rw   = d_in[1];
    const void* rbn  = d_in[2];
    const void* a1w  = d_in[3];
    const void* abn  = d_in[4];
    const void* a2w  = d_in[5];
    const void* rpw  = d_in[6];
    const void* rpbn = d_in[7];
    const void* ap1w = d_in[8];
    const void* apbn = d_in[9];
    const void* ap2w = d_in[10];
    const void* pjw  = d_in[11];
    const void* pjbn = d_in[12];

    char* W = (char*)d_ws;
    int* flag    = (int*)(W + 0);
    u16* rw_b    = (u16*)(W + 1024);          // 512x2048
    u16* rpw_b   = (u16*)(W + 2098176);       // 512x2048 (contiguous after rw_b)
    u16* a1w_b   = (u16*)(W + 4195328);       // 512x512
    u16* ap1w_b  = (u16*)(W + 4719616);       // contiguous
    u16* a2w_b   = (u16*)(W + 5243904);       // 3584x512 (pad rows garbage)
    u16* ap2w_b  = (u16*)(W + 8913920);       // contiguous
    u16* pjw_b   = (u16*)(W + 12583936);      // 2048x1024
    float* sbG1  = (float*)(W + 16778240);    // [s_c|b_c][s_d|b_d] 2048 f
    float* sbG2  = (float*)(W + 16786432);    // [s_c|b_c][s_d|b_d] 2048 f
    float* pj_sb = (float*)(W + 16794624);    // [s(2048)|b(2048)]
    u16* x_small_t = (u16*)(W + 16811264);    // 4x1024x2048 (reused: h1 c/d, then xp_t)
    u16* xc_t      = (u16*)(W + 33588480);    // 4x1024x512
    u16* xd_t      = (u16*)(W + 37782784);    // contiguous
    u16* xc_o      = (u16*)(W + 41977088);    // 4x512x1024
    u16* xd_o      = (u16*)(W + 46171392);    // contiguous
    u16* y_t       = (u16*)(W + 50365696);    // 4x1024x3584 (shared c/d)
    u16* Pc        = (u16*)(W + 79725824);    // 4x1024x1024
    u16* Pd        = (u16*)(W + 88114432);    // contiguous
    u16* cat_t     = (u16*)(W + 96503040);    // 4x1024x1024
    u16* h1        = x_small_t;               // 2 x [4096][512] after G1 done
    u16* xp_t      = x_small_t;               // [4096][2048] after agg

    // zero Pc+Pd (pad rows/cols must be exact zero for agg GEMM)
    hipMemsetAsync(Pc, 0, 16777216, stream);

    hipLaunchKernelGGL(probe_k, dim3(1), dim3(256), 0, stream, (const u16*)x, flag);

    WArgs wa;
    wa.src[0] = rw;   wa.dst[0] = rw_b;   wa.n[0] = 1048576;
    wa.src[1] = rpw;  wa.dst[1] = rpw_b;  wa.n[1] = 1048576;
    wa.src[2] = a1w;  wa.dst[2] = a1w_b;  wa.n[2] = 262144;
    wa.src[3] = ap1w; wa.dst[3] = ap1w_b; wa.n[3] = 262144;
    wa.src[4] = a2w;  wa.dst[4] = a2w_b;  wa.n[4] = 1782272;
    wa.src[5] = ap2w; wa.dst[5] = ap2w_b; wa.n[5] = 1782272;
    wa.src[6] = pjw;  wa.dst[6] = pjw_b;  wa.n[6] = 2097152;
    hipLaunchKernelGGL(wconv_all, dim3(2048, 7), dim3(256), 0, stream, wa, flag);

    BArgs ba;
    ba.src[0] = rbn;  ba.dst[0] = sbG1;        ba.C[0] = 512;  ba.sbN[0] = 512;
    ba.src[1] = rpbn; ba.dst[1] = sbG1 + 1024; ba.C[1] = 512;  ba.sbN[1] = 512;
    ba.src[2] = abn;  ba.dst[2] = sbG2;        ba.C[2] = 512;  ba.sbN[2] = 512;
    ba.src[3] = apbn; ba.dst[3] = sbG2 + 1024; ba.C[3] = 512;  ba.sbN[3] = 512;
    ba.src[4] = pjbn; ba.dst[4] = pj_sb;       ba.C[4] = 2048; ba.sbN[4] = 2048;
    hipLaunchKernelGGL(bnprep_all, dim3(8, 5), dim3(256), 0, stream, ba, flag);

    hipLaunchKernelGGL(subsampleT_k, dim3(32, 30, 4), dim3(256), 0, stream, x, x_small_t, flag);
    hipLaunchKernelGGL(copyx_k, dim3(27848), dim3(256), 0, stream, x, d_out, flag);

    const long sMid = (long)PP * MID;      // 524288 u16
    const long sMM  = (long)PP * MMpad;
    const long sO   = (long)MID * PP;      // 524288 u16
    const long sPPl = (long)PP * PP;       // 1048576 u16

    // G1: [xc_t|xd_t] = relu(bn(x_small @ {rw,rpw}^T)); M=4096, N=512, z=branch
    hipLaunchKernelGGL(mfma_gemm, dim3(8, 32, 2), dim3(256), 0, stream,
                       x_small_t, 0L, 0L,
                       rw_b, 0L, 1048576L,
                       xc_t, 0L, 4 * sMid, 1,
                       MID, CIN, sbG1, 512, 1024L, 1);
    // transposes for agg B operands (both branches in one launch, z=0..7)
    hipLaunchKernelGGL(transpose64_k, dim3(8, 16, 8), dim3(256), 0, stream,
                       xc_t, xc_o, PP, MID, sMid, sO);
    // G2: h1{c,d} = relu(bn(x{c,d}_t @ {a1w,ap1w}^T)); z=branch
    hipLaunchKernelGGL(mfma_gemm, dim3(8, 32, 2), dim3(256), 0, stream,
                       xc_t, 0L, 4 * sMid,
                       a1w_b, 0L, 262144L,
                       h1, 0L, 4 * sMid, 1,
                       MID, MID, sbG2, 512, 1024L, 1);
    // branch c: G3 + softmax (y_t buffer shared serially between branches)
    hipLaunchKernelGGL(mfma_gemm, dim3(56, 32, 1), dim3(256), 0, stream,
                       h1, 0L, 0L,
                       a2w_b, 0L, 0L,
                       y_t, 0L, 0L, 1,
                       MMpad, MID, (const float*)nullptr, 0, 0L, 0);
    hipLaunchKernelGGL(softmax_gather_k, dim3(900, 4), dim3(256), 0, stream, y_t, Pc, 1);
    // branch d
    hipLaunchKernelGGL(mfma_gemm, dim3(56, 32, 1), dim3(256), 0, stream,
                       h1 + 4 * sMid / 2, 0L, 0L,     // h1 + 2,097,152 u16
                       ap2w_b, 0L, 0L,
                       y_t, 0L, 0L, 1,
                       MMpad, MID, (const float*)nullptr, 0, 0L, 0);
    hipLaunchKernelGGL(softmax_gather_k, dim3(900, 4), dim3(256), 0, stream, y_t, Pd, 0);
    // agg: cat_t[:, :512] = Pc @ xc_o^T ; cat_t[:, 512:] = Pd @ xd_o^T; z=0..7
    hipLaunchKernelGGL(mfma_gemm, dim3(8, 8, 8), dim3(256), 0, stream,
                       Pc, sPPl, 4 * sPPl,
                       xc_o, sO, 4 * sO,
                       cat_t, sPPl, 512L, 4,
                       PP, PP, (const float*)nullptr, 0, 0L, 0);
    // projection: xp_t = relu(bn(cat_t @ pjw^T)); M=4096
    hipLaunchKernelGGL(mfma_gemm, dim3(32, 32, 1), dim3(256), 0, stream,
                       cat_t, 0L, 0L,
                       pjw_b, 0L, 0L,
                       xp_t, 0L, 0L, 1,
                       CIN, PP, pj_sb, 2048, 0L, 1);
    // upsample
    hipLaunchKernelGGL(upsample_k, dim3(32, 59, 4), dim3(256), 0, stream, xp_t, d_out, flag);
}